// Round 5
// baseline (572.813 us; speedup 1.0000x reference)
//
#include <hip/hip_runtime.h>

// ---------------- degree ----------------
__global__ void deg_kernel(const int* __restrict__ dst, int* __restrict__ deg, int E) {
    int e = blockIdx.x * blockDim.x + threadIdx.x;
    if (e < E) atomicAdd(&deg[dst[e]], 1);
}

// ---------------- scan1 (+ fused dinv) ----------------
__global__ void scan1_kernel(const int* __restrict__ deg, int* __restrict__ rowstart,
                             int* __restrict__ blockSums, float* __restrict__ dinv, int n) {
    __shared__ int tmp[256];
    int t = threadIdx.x;
    int i = blockIdx.x * 256 + t;
    int v = (i < n) ? deg[i] : 0;
    if (i < n) dinv[i] = rsqrtf((float)(v + 1));  // +1 = self loop
    tmp[t] = v;
    __syncthreads();
#pragma unroll
    for (int off = 1; off < 256; off <<= 1) {
        int add = (t >= off) ? tmp[t - off] : 0;
        __syncthreads();
        tmp[t] += add;
        __syncthreads();
    }
    if (i < n) rowstart[i] = tmp[t] - v;
    if (t == 255) blockSums[blockIdx.x] = tmp[255];
}

__global__ void scan2_kernel(int* __restrict__ blockSums, int nb) {
    __shared__ int tmp[512];
    int t = threadIdx.x;
    int v = (t < nb) ? blockSums[t] : 0;
    tmp[t] = v;
    __syncthreads();
#pragma unroll
    for (int off = 1; off < 512; off <<= 1) {
        int add = (t >= off) ? tmp[t - off] : 0;
        __syncthreads();
        tmp[t] += add;
        __syncthreads();
    }
    if (t < nb) blockSums[t] = tmp[t] - v;
}

__global__ void scan3_kernel(int* __restrict__ rowstart, const int* __restrict__ blockSums,
                             int* __restrict__ cursor, int n) {
    int i = blockIdx.x * blockDim.x + threadIdx.x;
    if (i < n) {
        int r = rowstart[i] + blockSums[i >> 8];
        rowstart[i] = r;
        cursor[i] = r;
    }
}

// ---------------- counting-sort edges by dst; pack (src, weight) ----------------
__global__ void sort_kernel(const int* __restrict__ src, const int* __restrict__ dst,
                            const float* __restrict__ dinv, int* __restrict__ cursor,
                            int2* __restrict__ edgeSorted, int E) {
    int e = blockIdx.x * blockDim.x + threadIdx.x;
    if (e < E) {
        int s = src[e], d = dst[e];
        int pos = atomicAdd(&cursor[d], 1);
        int2 p;
        p.x = s;
        p.y = __float_as_int(dinv[s] * dinv[d]);
        edgeSorted[pos] = p;
    }
}

// ---------------- GEMM1: h1[N,128] = x[N,128] @ W1[128,128] ----------------
// 256 threads, tile 64 nodes x 128 cols, register tile 8x4, k-step 4
__global__ __launch_bounds__(256) void gemm_nk128(const float* __restrict__ x,
                                                  const float* __restrict__ W,
                                                  float* __restrict__ h, int n) {
    __shared__ float xs[64][128];
    int t = threadIdx.x;
    int node0 = blockIdx.x * 64;
    // stage 64 rows (32 KB), 8 float4 per thread, guarded
#pragma unroll
    for (int i = 0; i < 8; i++) {
        int fi = t + 256 * i;            // 0..2047 float4 slots
        int row = fi >> 5, cv = fi & 31;
        float4 v = make_float4(0.f, 0.f, 0.f, 0.f);
        if (node0 + row < n) v = ((const float4*)x)[(size_t)(node0 + row) * 32 + cv];
        ((float4*)(&xs[0][0]))[fi] = v;
    }
    __syncthreads();

    int tx = t & 31, ty = t >> 5;    // cols 4tx..4tx+3 ; nodes ty+8i
    int c0 = tx * 4;
    float acc[8][4];
#pragma unroll
    for (int i = 0; i < 8; i++)
#pragma unroll
        for (int j = 0; j < 4; j++) acc[i][j] = 0.f;

    for (int k = 0; k < 128; k += 4) {
        float4 w0 = *(const float4*)(W + (k + 0) * 128 + c0);
        float4 w1 = *(const float4*)(W + (k + 1) * 128 + c0);
        float4 w2 = *(const float4*)(W + (k + 2) * 128 + c0);
        float4 w3 = *(const float4*)(W + (k + 3) * 128 + c0);
#pragma unroll
        for (int i = 0; i < 8; i++) {
            float4 xv = *(const float4*)(&xs[ty + 8 * i][k]);   // broadcast ds_read_b128
            acc[i][0] += xv.x * w0.x + xv.y * w1.x + xv.z * w2.x + xv.w * w3.x;
            acc[i][1] += xv.x * w0.y + xv.y * w1.y + xv.z * w2.y + xv.w * w3.y;
            acc[i][2] += xv.x * w0.z + xv.y * w1.z + xv.z * w2.z + xv.w * w3.z;
            acc[i][3] += xv.x * w0.w + xv.y * w1.w + xv.z * w2.w + xv.w * w3.w;
        }
    }
#pragma unroll
    for (int i = 0; i < 8; i++) {
        int node = node0 + ty + 8 * i;
        if (node < n)
            *(float4*)(h + (size_t)node * 128 + c0) =
                make_float4(acc[i][0], acc[i][1], acc[i][2], acc[i][3]);
    }
}

// ---------------- fused: gather1(h1) + b1 + relu -> LDS -> @W2 -> h3 ----------------
// 4 nodes per 256-thread block; gather: one wave per node (lane = 2 cols, float2);
// GEMM: thread = (node, col), 1 output each.
__global__ __launch_bounds__(256) void fused1_kernel(
        const int2* __restrict__ eS, const int* __restrict__ rowstart,
        const int* __restrict__ deg, const float* __restrict__ dinv,
        const float* __restrict__ h1, const float* __restrict__ b1,
        const float* __restrict__ W2, float* __restrict__ h3, int n) {
    __shared__ float xs[4][128];
    int t = threadIdx.x;
    int w = t >> 6, lane = t & 63;
    int g = blockIdx.x * 4 + w;

    if (g < n) {
        float di = dinv[g];
        float w0 = di * di;
        float2 v = ((const float2*)(h1 + (size_t)g * 128))[lane];
        float2 acc = make_float2(w0 * v.x, w0 * v.y);
        int beg = rowstart[g], end = beg + deg[g];
        int e = beg;
        for (; e + 8 <= end; e += 8) {
            int2 p0 = eS[e], p1 = eS[e+1], p2 = eS[e+2], p3 = eS[e+3];
            int2 p4 = eS[e+4], p5 = eS[e+5], p6 = eS[e+6], p7 = eS[e+7];
            float2 u0 = ((const float2*)(h1 + (size_t)p0.x * 128))[lane];
            float2 u1 = ((const float2*)(h1 + (size_t)p1.x * 128))[lane];
            float2 u2 = ((const float2*)(h1 + (size_t)p2.x * 128))[lane];
            float2 u3 = ((const float2*)(h1 + (size_t)p3.x * 128))[lane];
            float2 u4 = ((const float2*)(h1 + (size_t)p4.x * 128))[lane];
            float2 u5 = ((const float2*)(h1 + (size_t)p5.x * 128))[lane];
            float2 u6 = ((const float2*)(h1 + (size_t)p6.x * 128))[lane];
            float2 u7 = ((const float2*)(h1 + (size_t)p7.x * 128))[lane];
            acc.x += __int_as_float(p0.y) * u0.x; acc.y += __int_as_float(p0.y) * u0.y;
            acc.x += __int_as_float(p1.y) * u1.x; acc.y += __int_as_float(p1.y) * u1.y;
            acc.x += __int_as_float(p2.y) * u2.x; acc.y += __int_as_float(p2.y) * u2.y;
            acc.x += __int_as_float(p3.y) * u3.x; acc.y += __int_as_float(p3.y) * u3.y;
            acc.x += __int_as_float(p4.y) * u4.x; acc.y += __int_as_float(p4.y) * u4.y;
            acc.x += __int_as_float(p5.y) * u5.x; acc.y += __int_as_float(p5.y) * u5.y;
            acc.x += __int_as_float(p6.y) * u6.x; acc.y += __int_as_float(p6.y) * u6.y;
            acc.x += __int_as_float(p7.y) * u7.x; acc.y += __int_as_float(p7.y) * u7.y;
        }
        for (; e < end; e++) {
            int2 p = eS[e];
            float2 u = ((const float2*)(h1 + (size_t)p.x * 128))[lane];
            float wf = __int_as_float(p.y);
            acc.x += wf * u.x; acc.y += wf * u.y;
        }
        float2 b = ((const float2*)b1)[lane];
        acc.x = fmaxf(acc.x + b.x, 0.f);
        acc.y = fmaxf(acc.y + b.y, 0.f);
        *(float2*)(&xs[w][2 * lane]) = acc;          // h2 row in LDS
    }
    __syncthreads();

    // GEMM: node = t>>6 (same w), col = lane
    int gOut = blockIdx.x * 4 + w;
    if (gOut < n) {
        float acc = 0.f;
#pragma unroll
        for (int k = 0; k < 128; k += 4) {
            float4 xv = *(const float4*)(&xs[w][k]);   // uniform broadcast
            acc += xv.x * W2[(k + 0) * 64 + lane];
            acc += xv.y * W2[(k + 1) * 64 + lane];
            acc += xv.z * W2[(k + 2) * 64 + lane];
            acc += xv.w * W2[(k + 3) * 64 + lane];
        }
        h3[(size_t)gOut * 64 + lane] = acc;
    }
}

// ---------------- gather2: out = agg(h3) + b2 ; one wave per node, lane = col ----------------
__global__ __launch_bounds__(256) void gather2_kernel(
        const int2* __restrict__ eS, const int* __restrict__ rowstart,
        const int* __restrict__ deg, const float* __restrict__ dinv,
        const float* __restrict__ h3, const float* __restrict__ b2,
        float* __restrict__ out, int n) {
    int t = threadIdx.x;
    int w = t >> 6, lane = t & 63;
    int g = blockIdx.x * 4 + w;
    if (g >= n) return;
    float di = dinv[g];
    float w0 = di * di;
    float acc = w0 * h3[(size_t)g * 64 + lane];
    int beg = rowstart[g], end = beg + deg[g];
    int e = beg;
    for (; e + 8 <= end; e += 8) {
        int2 p0 = eS[e], p1 = eS[e+1], p2 = eS[e+2], p3 = eS[e+3];
        int2 p4 = eS[e+4], p5 = eS[e+5], p6 = eS[e+6], p7 = eS[e+7];
        float u0 = h3[(size_t)p0.x * 64 + lane];
        float u1 = h3[(size_t)p1.x * 64 + lane];
        float u2 = h3[(size_t)p2.x * 64 + lane];
        float u3 = h3[(size_t)p3.x * 64 + lane];
        float u4 = h3[(size_t)p4.x * 64 + lane];
        float u5 = h3[(size_t)p5.x * 64 + lane];
        float u6 = h3[(size_t)p6.x * 64 + lane];
        float u7 = h3[(size_t)p7.x * 64 + lane];
        acc += __int_as_float(p0.y) * u0 + __int_as_float(p1.y) * u1 +
               __int_as_float(p2.y) * u2 + __int_as_float(p3.y) * u3 +
               __int_as_float(p4.y) * u4 + __int_as_float(p5.y) * u5 +
               __int_as_float(p6.y) * u6 + __int_as_float(p7.y) * u7;
    }
    for (; e < end; e++) {
        int2 p = eS[e];
        acc += __int_as_float(p.y) * h3[(size_t)p.x * 64 + lane];
    }
    out[(size_t)g * 64 + lane] = acc + b2[lane];
}

extern "C" void kernel_launch(void* const* d_in, const int* in_sizes, int n_in,
                              void* d_out, int out_size, void* d_ws, size_t ws_size,
                              hipStream_t stream) {
    const float* x  = (const float*)d_in[0];
    const int*   ei = (const int*)d_in[1];
    const float* W1 = (const float*)d_in[2];
    const float* b1 = (const float*)d_in[3];
    const float* W2 = (const float*)d_in[4];
    const float* b2 = (const float*)d_in[5];
    float* out = (float*)d_out;

    const int n = in_sizes[0] / 128;   // 100000
    const int E = in_sizes[1] / 2;     // 1600000
    const int* src = ei;
    const int* dst = ei + E;
    const int nb = (n + 255) / 256;

    char* ws = (char*)d_ws;
    size_t off = 0;
    auto carve = [&](size_t bytes) -> char* {
        char* p = ws + off;
        off += (bytes + 255) & ~(size_t)255;
        return p;
    };
    int*   deg        = (int*)carve((size_t)n * 4);
    float* dinv       = (float*)carve((size_t)n * 4);
    int*   rowstart   = (int*)carve((size_t)n * 4);
    int*   cursor     = (int*)carve((size_t)n * 4);
    int*   blockSums  = (int*)carve((size_t)nb * 4);
    int2*  edgeSorted = (int2*)carve((size_t)E * 8);
    float* h1         = (float*)carve((size_t)n * 128 * 4);
    float* h3         = (float*)carve((size_t)n * 64 * 4);

    hipMemsetAsync(deg, 0, (size_t)n * 4, stream);

    deg_kernel<<<(E + 255) / 256, 256, 0, stream>>>(dst, deg, E);
    scan1_kernel<<<nb, 256, 0, stream>>>(deg, rowstart, blockSums, dinv, n);
    scan2_kernel<<<1, 512, 0, stream>>>(blockSums, nb);
    scan3_kernel<<<(n + 255) / 256, 256, 0, stream>>>(rowstart, blockSums, cursor, n);
    sort_kernel<<<(E + 255) / 256, 256, 0, stream>>>(src, dst, dinv, cursor, edgeSorted, E);

    // layer 1 GEMM
    gemm_nk128<<<(n + 63) / 64, 256, 0, stream>>>(x, W1, h1, n);
    // fused: gather1 + bias + relu + GEMM2 -> h3
    fused1_kernel<<<(n + 3) / 4, 256, 0, stream>>>(edgeSorted, rowstart, deg, dinv,
                                                   h1, b1, W2, h3, n);
    // gather2 + bias -> out
    gather2_kernel<<<(n + 3) / 4, 256, 0, stream>>>(edgeSorted, rowstart, deg, dinv,
                                                    h3, b2, out, n);
}